// Round 8
// baseline (1823.217 us; speedup 1.0000x reference)
//
#include <hip/hip_runtime.h>
#include <hip/hip_bf16.h>
#include <math.h>

#define B_   4096
#define T_   16
#define F_   256
#define U_   512
#define M_   8
#define K_   768    // F+U
#define NRS  4096   // U*M
#define NC   8192   // combined R|S output cols
#define LNT  1.1512925f  // 0.5*ln(10)

// chunk-major pre-tiled panel constants
#define XPH  32768   // x panel per (t,mh): 8 kt * 4096
#define XPT  1048576 // x per t: 32 mh * XPH
#define HPH  65536   // h panel per mh: 16 kt * 4096
#define BPH  98304   // B panel per NH: 24 kt * 4096
#define QPH  49152   // Bq panel per np: 24 kt * 2048

typedef __bf16 bf16_t;
typedef bf16_t bf16x8 __attribute__((ext_vector_type(8)));
typedef bf16_t bf16x4 __attribute__((ext_vector_type(4)));
typedef float  f32x4  __attribute__((ext_vector_type(4)));

__device__ inline void gl_lds16(const void* g, void* lds) {
    __builtin_amdgcn_global_load_lds(
        (const __attribute__((address_space(1))) unsigned int*)g,
        (__attribute__((address_space(3))) unsigned int*)lds, 16, 0, 0);
}

// ---------------------------------------------------------------------------
// FRAGMENT-DIRECT R|S GEMM: no LDS, no barriers. Chunk-major pre-tiling puts
// every MFMA fragment at a contiguous 16B/lane (256B/quarter-wave) global
// address, so each wave loads its a/b fragments straight from L2 into VGPRs.
// Register ping-pong (a0/b0 vs a1/b1) gives 1-tile prefetch depth; the
// compiler inserts the counted vmcnt before first use. 4 waves (2Mx2N) per
// block, wave tile 64x64, acc[4][4]. Per-CU LDS-port traffic: ZERO (R7's
// measured wall). Waves run free -> pure wave-level MFMA/mem overlap.
// Merged R+S (128-col tiles are purely one half; epilogue branch uniform).
// ---------------------------------------------------------------------------
__global__ __launch_bounds__(256) void gemm_rs_fd(
    const bf16_t* __restrict__ xt_t,   // [32 mh][8 kt][4][128][8]
    const bf16_t* __restrict__ ht,     // [32 mh][16 kt][4][128][8]
    const bf16_t* __restrict__ Bt,     // [64 NH][24 kt][4][128][8]
    const float*  __restrict__ biasP,  // [NC] (perm)
    const bf16_t* __restrict__ hhat,   // [B_][NRS]
    bf16_t* __restrict__ rh,           // [B_][U_]
    bf16_t* __restrict__ sbuf)         // [B_][NRS]
{
    const int tid  = threadIdx.x;
    const int lane = tid & 63;
    const int wave = tid >> 6;

    // bijective XCD swizzle: XCD c owns 16mh x 16NH (A 3.1MB + B 3.1MB / XCD).
    const int lin = blockIdx.y * 32 + blockIdx.x;   // 2048 blocks
    const int c = lin & 7, q = lin >> 3;            // q: 0..255
    const int mh = (c >> 2) * 16 + (q & 15);        // 0..31
    const int NH = (c & 3) * 16 + (q >> 4);         // 0..63
    const int m0 = mh * 128;

    const int wm = wave >> 1;          // 0..1
    const int wn = wave & 1;           // 0..1
    const int lr = lane & 15;
    const int kq = lane >> 4;          // k-chunk (8 of BK=32)

    const bf16_t* apx = xt_t + (size_t)mh * XPH;
    const bf16_t* aph = ht   + (size_t)mh * HPH;
    const bf16_t* bp  = Bt   + (size_t)NH * BPH;

    const int aoff = kq * 1024 + (wm * 64 + lr) * 8;
    const int boff = kq * 1024 + (wn * 64 + lr) * 8;

    f32x4 acc[4][4] = {};
    bf16x8 a0[4], b0[4], a1[4], b1[4];

#define ABASE(T) ((T) < 8 ? apx + (T) * 4096 : aph + ((T) - 8) * 4096)
#define LDA(D, T) do{ const bf16_t* _p = ABASE(T) + aoff;                      \
    D[0] = *(const bf16x8*)(_p);        D[1] = *(const bf16x8*)(_p + 128);     \
    D[2] = *(const bf16x8*)(_p + 256);  D[3] = *(const bf16x8*)(_p + 384); }while(0)
#define LDB(D, T) do{ const bf16_t* _p = bp + (T) * 4096 + boff;               \
    D[0] = *(const bf16x8*)(_p);        D[1] = *(const bf16x8*)(_p + 128);     \
    D[2] = *(const bf16x8*)(_p + 256);  D[3] = *(const bf16x8*)(_p + 384); }while(0)
#define MMA(A, B) do{ __builtin_amdgcn_s_setprio(1);                           \
    _Pragma("unroll") for (int i = 0; i < 4; ++i)                              \
      _Pragma("unroll") for (int j = 0; j < 4; ++j)                            \
        acc[i][j] = __builtin_amdgcn_mfma_f32_16x16x32_bf16(                   \
            A[i], B[j], acc[i][j], 0, 0, 0);                                   \
    __builtin_amdgcn_s_setprio(0); }while(0)

    LDA(a0, 0); LDB(b0, 0);
#pragma unroll
    for (int tt = 0; tt < 24; tt += 2) {
        if (tt + 1 < 24) { LDA(a1, tt + 1); LDB(b1, tt + 1); }
        MMA(a0, b0);
        if (tt + 2 < 24) { LDA(a0, tt + 2); LDB(b0, tt + 2); }
        MMA(a1, b1);
    }
#undef MMA
#undef LDB
#undef LDA
#undef ABASE

    // ------------------- fused softmax epilogue (proven math) --------------
    const int nb  = NH * 128 + wn * 64;   // global perm col base
    const int u3  = lane & 7;
    const int m0v = ((lane >> 3) & 1) * 4;
    const bool is_r = NH < 32;

    float bj4[4];
#pragma unroll
    for (int j = 0; j < 4; ++j) bj4[j] = biasP[nb + j * 16 + lr];

#pragma unroll
    for (int mi = 0; mi < 4; ++mi) {
        const int rowb = m0 + wm * 64 + mi * 16 + kq * 4;
#pragma unroll
        for (int r = 0; r < 4; ++r) {
            const int row = rowb + r;
            float e[4], sum = 0.f;
#pragma unroll
            for (int j = 0; j < 4; ++j) {
                float v = acc[mi][j][r] + bj4[j];
                float d = v - (float)(m0v + j) * LNT;
                e[j] = __expf(-d * d);
                sum += e[j];
            }
            sum += __shfl_xor(sum, 8, 64);
            const float inv = 1.0f / sum;
            if (is_r) {
                bf16x4 h4 = *(const bf16x4*)(hhat + (size_t)row * NRS + nb + u3 * 8 + m0v);
                float rhv = 0.f;
#pragma unroll
                for (int j = 0; j < 4; ++j) rhv += e[j] * inv * (float)h4[j];
                rhv += __shfl_xor(rhv, 8, 64);
                if ((lane & 8) == 0)
                    rh[(size_t)row * U_ + (nb >> 3) + u3] = (bf16_t)rhv;
            } else {
                bf16x4 pv;
#pragma unroll
                for (int j = 0; j < 4; ++j) pv[j] = (bf16_t)(e[j] * inv);
                *(bf16x4*)(sbuf + (size_t)row * NRS + (nb - NRS) + u3 * 8 + m0v) = pv;
            }
        }
    }
}

// ---------------------------------------------------------------------------
// q GEMM (64x64 tiles, grid 64x8=512, 4 waves 2x2) + fused state update.
// Unchanged from R7 (verified). Writes htile (chunk-major) for next step.
// ---------------------------------------------------------------------------
__global__ __launch_bounds__(256) void gemm_q_up(
    const bf16_t* __restrict__ xt_t,   // [32 mh][8 kt][4][128][8]
    const bf16_t* __restrict__ rh,     // [B_][U_]
    const bf16_t* __restrict__ Bqt,    // [8 np][24 kt][4][64][8]
    const float*  __restrict__ bq,
    const bf16_t* __restrict__ sbuf,
    bf16_t* __restrict__ hhat,
    bf16_t* __restrict__ hnext,        // hall slice t+1: [B_][U_]
    bf16_t* __restrict__ htile)        // [32 mh][16 kt][4][128][8]
{
    __shared__ __attribute__((aligned(16))) bf16_t As[4096];
    __shared__ __attribute__((aligned(16))) bf16_t Bs[4096];

    const int tid  = threadIdx.x;
    const int lane = tid & 63;
    const int wave = tid >> 6;
    const int m0 = blockIdx.x * 64;
    const int n0 = blockIdx.y * 64;
    const int wm = wave & 1;
    const int wn = wave >> 1;
    const int lr = lane & 15;
    const int kq = lane >> 4;

    const int chs = (tid >> 6) & 3;    // staging chunk
    const int rws = tid & 63;          // staging row

    const bf16_t* xp  = xt_t + (size_t)(m0 >> 7) * XPH;
    const int     r0  = m0 & 127;      // 0 or 64
    const bf16_t* bpq = Bqt + (size_t)(n0 >> 6) * QPH;

    f32x4 acc[2][2] = {};

    for (int kt = 0; kt < 12; ++kt) {
        __syncthreads();
        if (kt < 4) {
            gl_lds16(xp + ((size_t)((kt * 2 + 0) * 4 + chs) * 128 + r0 + rws) * 8,
                     (char*)As + tid * 16);
            gl_lds16(xp + ((size_t)((kt * 2 + 1) * 4 + chs) * 128 + r0 + rws) * 8,
                     (char*)As + tid * 16 + 4096);
        } else {
            const int cb = (kt - 4) * 64;
            gl_lds16(rh + (size_t)(m0 + rws) * U_ + cb + chs * 8,
                     (char*)As + tid * 16);
            gl_lds16(rh + (size_t)(m0 + rws) * U_ + cb + 32 + chs * 8,
                     (char*)As + tid * 16 + 4096);
        }
        gl_lds16(bpq + ((size_t)((kt * 2 + 0) * 4 + chs) * 64 + rws) * 8,
                 (char*)Bs + tid * 16);
        gl_lds16(bpq + ((size_t)((kt * 2 + 1) * 4 + chs) * 64 + rws) * 8,
                 (char*)Bs + tid * 16 + 4096);
        __syncthreads();

        bf16x8 af[4], bfr[4];
#pragma unroll
        for (int ks = 0; ks < 2; ks++)
#pragma unroll
            for (int i = 0; i < 2; i++) {
                af[i * 2 + ks]  = *(const bf16x8*)(As +
                    ((ks * 4 + kq) * 64 + wm * 32 + i * 16 + lr) * 8);
                bfr[i * 2 + ks] = *(const bf16x8*)(Bs +
                    ((ks * 4 + kq) * 64 + wn * 32 + i * 16 + lr) * 8);
            }
#pragma unroll
        for (int ks = 0; ks < 2; ks++)
#pragma unroll
            for (int i = 0; i < 2; i++)
#pragma unroll
                for (int j = 0; j < 2; j++)
                    acc[i][j] = __builtin_amdgcn_mfma_f32_16x16x32_bf16(
                        af[i * 2 + ks], bfr[j * 2 + ks], acc[i][j], 0, 0, 0);
    }

    const float DEC[8] = {0.0f, 0.9658531f, 0.9827783f, 0.9884856f,
                          0.9913518f, 0.9930754f, 0.9942261f, 0.9950489f};

#pragma unroll
    for (int i = 0; i < 2; i++) {
        const int rowb = m0 + wm * 32 + i * 16 + kq * 4;
#pragma unroll
        for (int j = 0; j < 2; j++) {
            const int u = n0 + wn * 32 + j * 16 + lr;
            const float bv = bq[u];
#pragma unroll
            for (int r = 0; r < 4; r++) {
                const int row = rowb + r;
                const float qv = tanhf(acc[i][j][r] + bv);
                const size_t base = (size_t)row * NRS + u * 8;
                bf16x8 s8 = *(const bf16x8*)(sbuf + base);
                bf16x8 h8 = *(const bf16x8*)(hhat + base);
                bf16x8 ho;
                float hs = 0.f;
#pragma unroll
                for (int m = 0; m < 8; m++) {
                    float s = (float)s8[m];
                    float h = (float)h8[m];
                    float hn = ((1.f - s) * h + s * qv) * DEC[m];
                    ho[m] = (bf16_t)hn;
                    hs += hn;
                }
                *(bf16x8*)(hhat + base) = ho;
                hnext[(size_t)row * U_ + u] = (bf16_t)hs;
                htile[((size_t)(row >> 7) * 16 + (u >> 5)) * 4096
                      + ((((u >> 3) & 3) * 128) + (row & 127)) * 8 + (u & 7)] = (bf16_t)hs;
            }
        }
    }
}

// dst[p][K_] = bf16(src[K_][NRS] col L), rows permuted within 64-groups.
__global__ void transpose_perm(const float* __restrict__ src, bf16_t* __restrict__ dst) {
    __shared__ float tl[32][33];
    int k0 = blockIdx.x * 32, n0 = blockIdx.y * 32;
    int tx = threadIdx.x & 31, ty = threadIdx.x >> 5;
#pragma unroll
    for (int i = 0; i < 32; i += 8)
        tl[ty + i][tx] = src[(size_t)(k0 + ty + i) * NRS + n0 + tx];
    __syncthreads();
#pragma unroll
    for (int i = 0; i < 32; i += 8) {
        int n = n0 + ty + i;
        int m = n & 7, u3v = (n >> 3) & 7;
        int p = (n & ~63) + (m & 3) * 16 + (m >> 2) * 8 + u3v;
        dst[(size_t)p * K_ + k0 + tx] = (bf16_t)tl[tx][ty + i];
    }
}

// BtN[NH][kt][4][128][8] (chunk-major) from WrsT [NC][K_] (perm rows).
__global__ void btile_build(const bf16_t* __restrict__ WrsT, bf16_t* __restrict__ Bt) {
    int n = blockIdx.x / 3;
    int k = (blockIdx.x % 3) * 256 + threadIdx.x;
    int NH = n >> 7, prow = n & 127;
    int kt = k >> 5, ch = (k >> 3) & 3, e = k & 7;
    Bt[(size_t)NH * BPH + (((size_t)kt * 4 + ch) * 128 + prow) * 8 + e]
        = WrsT[(size_t)n * K_ + k];
}

// plain transpose: dst[N][K_] = bf16(src[K_][N]^T)
__global__ void transpose_plain(const float* __restrict__ src, bf16_t* __restrict__ dst, int N) {
    __shared__ float tl[32][33];
    int k0 = blockIdx.x * 32, n0 = blockIdx.y * 32;
    int tx = threadIdx.x & 31, ty = threadIdx.x >> 5;
#pragma unroll
    for (int i = 0; i < 32; i += 8)
        tl[ty + i][tx] = src[(size_t)(k0 + ty + i) * N + n0 + tx];
    __syncthreads();
#pragma unroll
    for (int i = 0; i < 32; i += 8)
        dst[(size_t)(n0 + ty + i) * K_ + k0 + tx] = (bf16_t)tl[tx][ty + i];
}

// BqtN[np][kt][4][64][8] (chunk-major) from WqT [U_][K_].
__global__ void bqtile_build(const bf16_t* __restrict__ WqT, bf16_t* __restrict__ Bqt) {
    int n = blockIdx.x / 3;
    int k = (blockIdx.x % 3) * 256 + threadIdx.x;
    int np = n >> 6, prow = n & 63;
    int kt = k >> 5, ch = (k >> 3) & 3, e = k & 7;
    Bqt[(size_t)np * QPH + (((size_t)kt * 4 + ch) * 64 + prow) * 8 + e]
        = WqT[(size_t)n * K_ + k];
}

__global__ void bias_perm(const float* __restrict__ b_r, const float* __restrict__ b_s,
                          float* __restrict__ biasP) {
    int p = blockIdx.x * 256 + threadIdx.x;  // NC
    int pr = p & 63, j = pr >> 4, lr = pr & 15;
    int L = (p & ~63) + (lr & 7) * 8 + ((lr >> 3) & 1) * 4 + j;
    biasP[p] = (L < NRS) ? b_r[L] : b_s[L - NRS];
}

// xtN[t][mh][kt][4][128][8] (chunk-major) from x f32 [B][T][F].
// Vectorized: one thread = one 8-f chunk (2x float4 in, 1x bf16x8 out).
__global__ void xtile_build(const float* __restrict__ x, bf16_t* __restrict__ xt) {
    int idx = blockIdx.x * 256 + threadIdx.x;  // B_*T_*F_/8
    int b = idx >> 9;              // 512 chunks per b (T_ * F_/8)
    int rem = idx & 511;
    int t = rem >> 5, c8 = rem & 31;
    int f0 = c8 * 8;
    const float* src = x + ((size_t)b * T_ + t) * F_ + f0;
    float4 v0 = *(const float4*)(src);
    float4 v1 = *(const float4*)(src + 4);
    bf16x8 o;
    o[0] = (bf16_t)v0.x; o[1] = (bf16_t)v0.y; o[2] = (bf16_t)v0.z; o[3] = (bf16_t)v0.w;
    o[4] = (bf16_t)v1.x; o[5] = (bf16_t)v1.y; o[6] = (bf16_t)v1.z; o[7] = (bf16_t)v1.w;
    int mh = b >> 7, prow = b & 127;
    int kt = f0 >> 5, ch = (f0 >> 3) & 3;
    *(bf16x8*)(xt + (size_t)t * XPT + (size_t)mh * XPH
               + (((size_t)kt * 4 + ch) * 128 + prow) * 8) = o;
}

// One launch for all T steps: out[b,t,:] = hall[t][b][:] @ Wout + bout.
__global__ __launch_bounds__(256) void out_all(
    const bf16_t* __restrict__ hall,   // [T_][B_][U_] (slices 1..16 of alloc)
    const float* __restrict__ Wout,
    const float* __restrict__ bout,
    float* __restrict__ out)
{
    int row = blockIdx.x * 4 + (threadIdx.x >> 6);  // t*B_ + b
    int lane = threadIdx.x & 63;
    bf16x8 h8 = *(const bf16x8*)(hall + (size_t)row * U_ + lane * 8);
    float p0 = 0, p1 = 0, p2 = 0;
#pragma unroll
    for (int k = 0; k < 8; k++) {
        float h = (float)h8[k];
        int u = lane * 8 + k;
        p0 += h * Wout[u * 3 + 0];
        p1 += h * Wout[u * 3 + 1];
        p2 += h * Wout[u * 3 + 2];
    }
    for (int off = 32; off; off >>= 1) {
        p0 += __shfl_down(p0, off, 64);
        p1 += __shfl_down(p1, off, 64);
        p2 += __shfl_down(p2, off, 64);
    }
    if (lane == 0) {
        int t = row >> 12, b = row & (B_ - 1);
        size_t o = ((size_t)b * T_ + t) * 3;
        out[o + 0] = p0 + bout[0];
        out[o + 1] = p1 + bout[1];
        out[o + 2] = p2 + bout[2];
    }
}

extern "C" void kernel_launch(void* const* d_in, const int* in_sizes, int n_in,
                              void* d_out, int out_size, void* d_ws, size_t ws_size,
                              hipStream_t stream) {
    const float* x   = (const float*)d_in[0];
    const float* W_r = (const float*)d_in[1];
    const float* b_r = (const float*)d_in[2];
    const float* W_q = (const float*)d_in[3];
    const float* b_q = (const float*)d_in[4];
    const float* W_s = (const float*)d_in[5];
    const float* b_s = (const float*)d_in[6];
    const float* W_o = (const float*)d_in[7];
    const float* b_o = (const float*)d_in[8];
    float* out = (float*)d_out;

    char* ws = (char*)d_ws;
    bf16_t* hhat  = (bf16_t*)ws; ws += (size_t)B_ * NRS * 2;           // 33.5 MB
    bf16_t* sbuf  = (bf16_t*)ws; ws += (size_t)B_ * NRS * 2;           // 33.5 MB
    bf16_t* xtile = (bf16_t*)ws; ws += (size_t)T_ * XPT * 2;           // 33.5 MB
    bf16_t* hall  = (bf16_t*)ws; ws += (size_t)(T_ + 1) * B_ * U_ * 2; // 71 MB
    bf16_t* rh    = (bf16_t*)ws; ws += (size_t)B_ * U_ * 2;            // 4.2 MB
    bf16_t* WrsT  = (bf16_t*)ws; ws += (size_t)NC * K_ * 2;            // 12.6 MB
    bf16_t* Btile = (bf16_t*)ws; ws += (size_t)NC * K_ * 2;            // 12.6 MB
    bf16_t* htile = (bf16_t*)ws; ws += (size_t)32 * HPH * 2;           // 4.2 MB
    bf16_t* WqT   = (bf16_t*)ws; ws += (size_t)U_ * K_ * 2;            // 0.79 MB
    bf16_t* Bqtil = (bf16_t*)ws; ws += (size_t)8 * QPH * 2;            // 0.79 MB
    float*  biasP = (float*)ws;  ws += (size_t)NC * 4;                 // 32 KB

    hipMemsetAsync(hhat, 0, (size_t)B_ * NRS * 2, stream);
    hipMemsetAsync(htile, 0, (size_t)32 * HPH * 2, stream);  // h(-1)=0 tiled
    xtile_build<<<B_ * T_ * F_ / 8 / 256, 256, 0, stream>>>(x, xtile);
    transpose_perm<<<dim3(K_ / 32, NRS / 32), 256, 0, stream>>>(W_r, WrsT);
    transpose_perm<<<dim3(K_ / 32, NRS / 32), 256, 0, stream>>>(W_s, WrsT + (size_t)NRS * K_);
    btile_build<<<NC * 3, 256, 0, stream>>>(WrsT, Btile);
    transpose_plain<<<dim3(K_ / 32, U_ / 32), 256, 0, stream>>>(W_q, WqT, U_);
    bqtile_build<<<U_ * 3, 256, 0, stream>>>(WqT, Bqtil);
    bias_perm<<<NC / 256, 256, 0, stream>>>(b_r, b_s, biasP);

    for (int t = 0; t < T_; t++) {
        const bf16_t* xt_t = xtile + (size_t)t * XPT;
        bf16_t*       hn   = hall + (size_t)(t + 1) * B_ * U_;  // h(t)
        gemm_rs_fd<<<dim3(32, 64), 256, 0, stream>>>(xt_t, htile, Btile, biasP, hhat, rh, sbuf);
        gemm_q_up<<<dim3(64, 8), 256, 0, stream>>>(xt_t, rh, Bqtil, b_q, sbuf, hhat, hn, htile);
    }
    out_all<<<B_ * T_ / 4, 256, 0, stream>>>(hall + (size_t)B_ * U_, W_o, b_o, out);
}

// Round 9
// 1491.741 us; speedup vs baseline: 1.2222x; 1.2222x over previous
//
#include <hip/hip_runtime.h>
#include <hip/hip_bf16.h>
#include <math.h>

#define B_   4096
#define T_   16
#define F_   256
#define U_   512
#define M_   8
#define K_   768    // F+U
#define NRS  4096   // U*M
#define NC   8192   // combined R|S output cols
#define LNT  1.1512925f  // 0.5*ln(10)

// chunk-major pre-tiled panel constants
#define XPH  32768   // x panel per (t,mh): 8 kt * 4096
#define XPT  1048576 // x per t: 32 mh * XPH
#define HPH  65536   // h panel per mh: 16 kt * 4096
#define BPH  98304   // B panel per NH: 24 kt * 4096
#define QPP  12288   // Bq16 panel per nh: 24 kt * 512

typedef __bf16 bf16_t;
typedef bf16_t bf16x8 __attribute__((ext_vector_type(8)));
typedef bf16_t bf16x4 __attribute__((ext_vector_type(4)));
typedef float  f32x4  __attribute__((ext_vector_type(4)));

__device__ inline void gl_lds16(const void* g, void* lds) {
    __builtin_amdgcn_global_load_lds(
        (const __attribute__((address_space(1))) unsigned int*)g,
        (__attribute__((address_space(3))) unsigned int*)lds, 16, 0, 0);
}

#define VMCNT(n) asm volatile("s_waitcnt vmcnt(" #n ")" ::: "memory")
#define LGKM0()  asm volatile("s_waitcnt lgkmcnt(0)" ::: "memory")
#define BAR()    __builtin_amdgcn_s_barrier()

// Chunk-major BK=32 slot: [4 ch][128 rows][8 bf16] = 8 KB; chunk c holds
// k=c*8..+7. Staging = 2 linear 16B loads/thread (256 thr). Reads: 16-lane
// quarter (fixed chunk) reads 16 consecutive rows x 16B -> 2-way free.
__device__ inline void stage8(const bf16_t* src, bf16_t* dst, int tid) {
    gl_lds16(src + tid * 8,        (char*)dst + tid * 16);
    gl_lds16(src + tid * 8 + 2048, (char*)dst + tid * 16 + 4096);
}

// ---------------------------------------------------------------------------
// R-half GEMM (verbatim R7 gemm_half<1>): 128x128 tile, 4 waves (2Mx2N),
// BK=32, 24 tiles, single-barrier parity schedule, 32 KiB LDS, 4 blk/CU.
// Epilogue: softmax + r*hhat reduce -> rh.
// ---------------------------------------------------------------------------
__global__ __launch_bounds__(256, 4) void gemm_r(
    const bf16_t* __restrict__ xt_t,   // [32 mh][8 kt][4][128][8]
    const bf16_t* __restrict__ ht,     // [32 mh][16 kt][4][128][8] (h(t-1))
    const bf16_t* __restrict__ Bt,     // [64 NH][24 kt][4][128][8]
    const float*  __restrict__ biasP,  // [NC] (perm)
    const bf16_t* __restrict__ hhat,   // [B_][NRS]
    bf16_t* __restrict__ rh)           // [B_][U_]
{
    __shared__ __attribute__((aligned(16))) bf16_t Ahl[2][4096];
    __shared__ __attribute__((aligned(16))) bf16_t Bhl[2][4096];

    const int tid  = threadIdx.x;
    const int lane = tid & 63;
    const int wave = tid >> 6;

    const int lin = blockIdx.y * 32 + blockIdx.x;   // 1024 blocks
    const int c = lin & 7, q = lin >> 3;
    const int mh = (c >> 1) * 8 + (q & 7);
    const int nh = (c & 1) * 16 + (q >> 3);
    const int m0 = mh * 128;
    const int NH = nh;                              // R half

    const int wm = wave >> 1;
    const int wn = wave & 1;
    const int lr = lane & 15;
    const int kq = lane >> 4;

    const bf16_t* xp = xt_t + (size_t)mh * XPH;
    const bf16_t* hp = ht   + (size_t)mh * HPH;
    const bf16_t* bp = Bt   + (size_t)NH * BPH;

    const int aoff = kq * 1024 + (wm * 64 + lr) * 8;
    const int boff = kq * 1024 + (wn * 64 + lr) * 8;

    f32x4 acc[4][4] = {};

    stage8(xp, &Ahl[0][0], tid);
    stage8(bp, &Bhl[0][0], tid);
    VMCNT(0);
    BAR();

#pragma unroll
    for (int tt = 0; tt < 24; ++tt) {
        const int p = tt & 1, pn = p ^ 1;
        if (tt < 23) {
            const bf16_t* as = (tt + 1 < 8) ? xp + (tt + 1) * 4096
                                            : hp + (tt + 1 - 8) * 4096;
            stage8(as, &Ahl[pn][0], tid);
            stage8(bp + (tt + 1) * 4096, &Bhl[pn][0], tid);
        }
        bf16x8 a[4], b[4];
#pragma unroll
        for (int i = 0; i < 4; ++i)
            a[i] = *(const bf16x8*)(&Ahl[p][0] + aoff + i * 128);
#pragma unroll
        for (int j = 0; j < 4; ++j)
            b[j] = *(const bf16x8*)(&Bhl[p][0] + boff + j * 128);
        LGKM0();
        __builtin_amdgcn_s_setprio(1);
#pragma unroll
        for (int i = 0; i < 4; ++i)
#pragma unroll
            for (int j = 0; j < 4; ++j)
                acc[i][j] = __builtin_amdgcn_mfma_f32_16x16x32_bf16(
                    a[i], b[j], acc[i][j], 0, 0, 0);
        __builtin_amdgcn_s_setprio(0);
        VMCNT(0);
        BAR();
    }

    const int nb  = NH * 128 + wn * 64;
    const int u3  = lane & 7;
    const int m0v = ((lane >> 3) & 1) * 4;

    float bj4[4];
#pragma unroll
    for (int j = 0; j < 4; ++j) bj4[j] = biasP[nb + j * 16 + lr];

#pragma unroll
    for (int mi = 0; mi < 4; ++mi) {
        const int rowb = m0 + wm * 64 + mi * 16 + kq * 4;
#pragma unroll
        for (int r = 0; r < 4; ++r) {
            const int row = rowb + r;
            float e[4], sum = 0.f;
#pragma unroll
            for (int j = 0; j < 4; ++j) {
                float v = acc[mi][j][r] + bj4[j];
                float d = v - (float)(m0v + j) * LNT;
                e[j] = __expf(-d * d);
                sum += e[j];
            }
            sum += __shfl_xor(sum, 8, 64);
            const float inv = 1.0f / sum;
            bf16x4 h4 = *(const bf16x4*)(hhat + (size_t)row * NRS + nb + u3 * 8 + m0v);
            float rhv = 0.f;
#pragma unroll
            for (int j = 0; j < 4; ++j) rhv += e[j] * inv * (float)h4[j];
            rhv += __shfl_xor(rhv, 8, 64);
            if ((lane & 8) == 0)
                rh[(size_t)row * U_ + (nb >> 3) + u3] = (bf16_t)rhv;
        }
    }
}

// ---------------------------------------------------------------------------
// FUSED S-GEMM + q-GEMM + state update (sbuf eliminated). Block = 128 rows x
// 128 S-cols (= 16 u), grid 1024, 4 waves, 40 KiB LDS -> 4 blk/CU.
// Phase 1: q-GEMM (128x16 over K): A = [x | rh] (x linear from xtile; rh
//   scattered gl_lds), B = Wq 16-col panel (1KB/tile, wave0 stages). Results
//   tanh'd into q_lds (8KB) -> no register overlap with the S accumulators.
// Phase 2: S K-loop — verbatim R7 schedule.
// Phase 3: softmax -> s_ki in-register; update hn=((1-s)h+s q)DEC in place
//   (each (row,u,m) owned by exactly one block); write hhat, hall, htile(w).
// FIRST=1 (t=0): h=rh=hhat=0 -> only 8 x-tiles in both K-loops, no hhat read.
// htile double-buffered across steps (read t-1 / write t).
// ---------------------------------------------------------------------------
template <int FIRST>
__global__ __launch_bounds__(256, 4) void gemm_sq(
    const bf16_t* __restrict__ xt_t,   // [32 mh][8 kt][4][128][8]
    const bf16_t* __restrict__ htr,    // h(t-1) tiles (read)
    const bf16_t* __restrict__ Bt,     // [64 NH][24 kt][4][128][8]
    const float*  __restrict__ biasP,  // [NC] (perm)
    const bf16_t* __restrict__ rh,     // [B_][U_]
    const bf16_t* __restrict__ Bq16,   // [32 nh][24 kt][4][16][8]
    const float*  __restrict__ bq,     // [U_]
    bf16_t* __restrict__ hhat,         // [B_][NRS] read(t-1)+write(t)
    bf16_t* __restrict__ hnext,        // hall slice t+1: [B_][U_]
    bf16_t* __restrict__ htw)          // h(t) tiles (write)
{
    __shared__ __attribute__((aligned(16))) bf16_t Ahl[2][4096];  // 16 KB
    __shared__ __attribute__((aligned(16))) bf16_t Bhl[2][4096];  // 16 KB
    __shared__ __attribute__((aligned(16))) float  qls[2048];     // 8 KB q[128][16]

    const int tid  = threadIdx.x;
    const int lane = tid & 63;
    const int wave = tid >> 6;

    const int lin = blockIdx.y * 32 + blockIdx.x;   // 1024 blocks
    const int c = lin & 7, qq = lin >> 3;
    const int mh = (c >> 1) * 8 + (qq & 7);
    const int nh = (c & 1) * 16 + (qq >> 3);
    const int m0 = mh * 128;
    const int NH = 32 + nh;                         // S half

    const int wm = wave >> 1;
    const int wn = wave & 1;
    const int lr = lane & 15;
    const int kq = lane >> 4;

    const bf16_t* xp = xt_t + (size_t)mh * XPH;
    const bf16_t* hp = htr  + (size_t)mh * HPH;
    const bf16_t* bp = Bt   + (size_t)NH * BPH;
    const bf16_t* bqp = Bq16 + (size_t)nh * QPP;

    const int NT = FIRST ? 8 : 24;

    // ---------------- Phase 1: q GEMM (q results -> qls) -------------------
    {
        // Bq parity slabs live in Bhl[0][0..1023] (2 x 512 elems).
        bf16_t* bslab = &Bhl[0][0];
        f32x4 accq[2] = {};

        // A stage kt: kt<8 -> x (linear); else rh scattered (inv layout).
        const int rws = tid & 127, chs = tid >> 7;   // rh staging decomposition

#define STAGE_AQ(KT, DST) do{                                                  \
        if ((KT) < 8) stage8(xp + (KT) * 4096, DST, tid);                      \
        else {                                                                 \
            const int cb_ = ((KT) - 8) * 32;                                   \
            gl_lds16(rh + (size_t)(m0 + rws) * U_ + cb_ + chs * 8,             \
                     (char*)(DST) + tid * 16);                                 \
            gl_lds16(rh + (size_t)(m0 + rws) * U_ + cb_ + 16 + chs * 8,        \
                     (char*)(DST) + tid * 16 + 4096);                          \
        } }while(0)
#define STAGE_BQ(KT, P) do{ if (wave == 0)                                     \
        gl_lds16(bqp + (KT) * 512 + lane * 8,                                  \
                 (char*)bslab + (P) * 1024 + lane * 16); }while(0)

        STAGE_AQ(0, &Ahl[0][0]);
        STAGE_BQ(0, 0);
        VMCNT(0);
        BAR();
#pragma unroll
        for (int kt = 0; kt < NT; ++kt) {
            const int p = kt & 1, pn = p ^ 1;
            if (kt < NT - 1) { STAGE_AQ(kt + 1, &Ahl[pn][0]); STAGE_BQ(kt + 1, pn); }
            bf16x8 aq[2], bqf;
#pragma unroll
            for (int i = 0; i < 2; ++i)
                aq[i] = *(const bf16x8*)(&Ahl[p][0] + kq * 1024
                                         + (wave * 32 + i * 16 + lr) * 8);
            bqf = *(const bf16x8*)(bslab + p * 512 + (kq * 16 + lr) * 8);
            LGKM0();
#pragma unroll
            for (int i = 0; i < 2; ++i)
                accq[i] = __builtin_amdgcn_mfma_f32_16x16x32_bf16(
                    aq[i], bqf, accq[i], 0, 0, 0);
            VMCNT(0);
            BAR();
        }
#undef STAGE_AQ
#undef STAGE_BQ

        const float bqv = bq[nh * 16 + lr];
#pragma unroll
        for (int i = 0; i < 2; ++i)
#pragma unroll
            for (int r = 0; r < 4; ++r)
                qls[(wave * 32 + i * 16 + kq * 4 + r) * 16 + lr] =
                    tanhf(accq[i][r] + bqv);
        BAR();
    }

    // ---------------- Phase 2: S GEMM (verbatim R7 schedule) ---------------
    const int aoff = kq * 1024 + (wm * 64 + lr) * 8;
    const int boff = kq * 1024 + (wn * 64 + lr) * 8;

    f32x4 acc[4][4] = {};

    stage8(xp, &Ahl[0][0], tid);
    stage8(bp, &Bhl[0][0], tid);
    VMCNT(0);
    BAR();

#pragma unroll
    for (int tt = 0; tt < NT; ++tt) {
        const int p = tt & 1, pn = p ^ 1;
        if (tt < NT - 1) {
            const bf16_t* as = (tt + 1 < 8) ? xp + (tt + 1) * 4096
                                            : hp + (tt + 1 - 8) * 4096;
            stage8(as, &Ahl[pn][0], tid);
            stage8(bp + (tt + 1) * 4096, &Bhl[pn][0], tid);
        }
        bf16x8 a[4], b[4];
#pragma unroll
        for (int i = 0; i < 4; ++i)
            a[i] = *(const bf16x8*)(&Ahl[p][0] + aoff + i * 128);
#pragma unroll
        for (int j = 0; j < 4; ++j)
            b[j] = *(const bf16x8*)(&Bhl[p][0] + boff + j * 128);
        LGKM0();
        __builtin_amdgcn_s_setprio(1);
#pragma unroll
        for (int i = 0; i < 4; ++i)
#pragma unroll
            for (int j = 0; j < 4; ++j)
                acc[i][j] = __builtin_amdgcn_mfma_f32_16x16x32_bf16(
                    a[i], b[j], acc[i][j], 0, 0, 0);
        __builtin_amdgcn_s_setprio(0);
        VMCNT(0);
        BAR();
    }

    // ---------------- Phase 3: softmax + state update ----------------------
    const int nb  = NH * 128 + wn * 64;          // perm col base (S range)
    const int u3  = lane & 7;
    const int m0v = ((lane >> 3) & 1) * 4;
    const int hcol = nh * 128 + wn * 64;         // hhat col base

    const float DECL[4] = {0.0f, 0.9658531f, 0.9827783f, 0.9884856f};
    const float DECH[4] = {0.9913518f, 0.9930754f, 0.9942261f, 0.9950489f};

    float bj4[4];
#pragma unroll
    for (int j = 0; j < 4; ++j) bj4[j] = biasP[nb + j * 16 + lr];

#pragma unroll
    for (int mi = 0; mi < 4; ++mi) {
        const int rowb = m0 + wm * 64 + mi * 16 + kq * 4;
        const int rlb  = wm * 64 + mi * 16 + kq * 4;
#pragma unroll
        for (int r = 0; r < 4; ++r) {
            const int row = rowb + r;
            float e[4], sum = 0.f;
#pragma unroll
            for (int j = 0; j < 4; ++j) {
                float v = acc[mi][j][r] + bj4[j];
                float d = v - (float)(m0v + j) * LNT;
                e[j] = __expf(-d * d);
                sum += e[j];
            }
            sum += __shfl_xor(sum, 8, 64);
            const float inv = 1.0f / sum;
            const float qv = qls[(rlb + r) * 16 + wn * 8 + u3];

            const size_t ha = (size_t)row * NRS + hcol + u3 * 8 + m0v;
            bf16x4 h4;
            if (!FIRST) h4 = *(const bf16x4*)(hhat + ha);
            bf16x4 ho;
            float hs = 0.f;
#pragma unroll
            for (int j = 0; j < 4; ++j) {
                float s = e[j] * inv;
                float h = FIRST ? 0.f : (float)h4[j];
                float dec = m0v ? DECH[j] : DECL[j];
                float hn = ((1.f - s) * h + s * qv) * dec;
                ho[j] = (bf16_t)hn;
                hs += hn;
            }
            *(bf16x4*)(hhat + ha) = ho;
            hs += __shfl_xor(hs, 8, 64);
            if ((lane & 8) == 0) {
                const int u = nh * 16 + wn * 8 + u3;
                hnext[(size_t)row * U_ + u] = (bf16_t)hs;
                htw[((size_t)(row >> 7) * 16 + (u >> 5)) * 4096
                    + ((((u >> 3) & 3) * 128) + (row & 127)) * 8 + (u & 7)] = (bf16_t)hs;
            }
        }
    }
}

// dst[p][K_] = bf16(src[K_][NRS] col L), rows permuted within 64-groups.
__global__ void transpose_perm(const float* __restrict__ src, bf16_t* __restrict__ dst) {
    __shared__ float tl[32][33];
    int k0 = blockIdx.x * 32, n0 = blockIdx.y * 32;
    int tx = threadIdx.x & 31, ty = threadIdx.x >> 5;
#pragma unroll
    for (int i = 0; i < 32; i += 8)
        tl[ty + i][tx] = src[(size_t)(k0 + ty + i) * NRS + n0 + tx];
    __syncthreads();
#pragma unroll
    for (int i = 0; i < 32; i += 8) {
        int n = n0 + ty + i;
        int m = n & 7, u3v = (n >> 3) & 7;
        int p = (n & ~63) + (m & 3) * 16 + (m >> 2) * 8 + u3v;
        dst[(size_t)p * K_ + k0 + tx] = (bf16_t)tl[tx][ty + i];
    }
}

// BtN[NH][kt][4][128][8] (chunk-major) from WrsT [NC][K_] (perm rows).
__global__ void btile_build(const bf16_t* __restrict__ WrsT, bf16_t* __restrict__ Bt) {
    int n = blockIdx.x / 3;
    int k = (blockIdx.x % 3) * 256 + threadIdx.x;
    int NH = n >> 7, prow = n & 127;
    int kt = k >> 5, ch = (k >> 3) & 3, e = k & 7;
    Bt[(size_t)NH * BPH + (((size_t)kt * 4 + ch) * 128 + prow) * 8 + e]
        = WrsT[(size_t)n * K_ + k];
}

// Bq16[nh][kt][4 ch][16][8] from W_q f32 [K_][U_] (coalesced src read).
__global__ void bq16_build(const float* __restrict__ Wq, bf16_t* __restrict__ Bq16) {
    int i = blockIdx.x * 256 + threadIdx.x;   // K_*U_
    int k = i >> 9, u = i & 511;
    int nh = u >> 4, ul = u & 15;
    int kt = k >> 5, ch = (k >> 3) & 3, e = k & 7;
    Bq16[(size_t)nh * QPP + ((size_t)kt * 4 + ch) * 128 + ul * 8 + e] = (bf16_t)Wq[i];
}

__global__ void bias_perm(const float* __restrict__ b_r, const float* __restrict__ b_s,
                          float* __restrict__ biasP) {
    int p = blockIdx.x * 256 + threadIdx.x;  // NC
    int pr = p & 63, j = pr >> 4, lr = pr & 15;
    int L = (p & ~63) + (lr & 7) * 8 + ((lr >> 3) & 1) * 4 + j;
    biasP[p] = (L < NRS) ? b_r[L] : b_s[L - NRS];
}

// xtN[t][mh][kt][4][128][8] (chunk-major) from x f32 [B][T][F]. Vectorized:
// one thread = one 8-f chunk (2x float4 in, 1x bf16x8 out).
__global__ void xtile_build(const float* __restrict__ x, bf16_t* __restrict__ xt) {
    int idx = blockIdx.x * 256 + threadIdx.x;  // B_*T_*F_/8
    int b = idx >> 9;
    int rem = idx & 511;
    int t = rem >> 5, c8 = rem & 31;
    int f0 = c8 * 8;
    const float* src = x + ((size_t)b * T_ + t) * F_ + f0;
    float4 v0 = *(const float4*)(src);
    float4 v1 = *(const float4*)(src + 4);
    bf16x8 o;
    o[0] = (bf16_t)v0.x; o[1] = (bf16_t)v0.y; o[2] = (bf16_t)v0.z; o[3] = (bf16_t)v0.w;
    o[4] = (bf16_t)v1.x; o[5] = (bf16_t)v1.y; o[6] = (bf16_t)v1.z; o[7] = (bf16_t)v1.w;
    int mh = b >> 7, prow = b & 127;
    int kt = f0 >> 5, ch = (f0 >> 3) & 3;
    *(bf16x8*)(xt + (size_t)t * XPT + (size_t)mh * XPH
               + (((size_t)kt * 4 + ch) * 128 + prow) * 8) = o;
}

// One launch for all T steps: out[b,t,:] = hall[t][b][:] @ Wout + bout.
__global__ __launch_bounds__(256) void out_all(
    const bf16_t* __restrict__ hall,   // [T_][B_][U_] (slices 1..16 of alloc)
    const float* __restrict__ Wout,
    const float* __restrict__ bout,
    float* __restrict__ out)
{
    int row = blockIdx.x * 4 + (threadIdx.x >> 6);  // t*B_ + b
    int lane = threadIdx.x & 63;
    bf16x8 h8 = *(const bf16x8*)(hall + (size_t)row * U_ + lane * 8);
    float p0 = 0, p1 = 0, p2 = 0;
#pragma unroll
    for (int k = 0; k < 8; k++) {
        float h = (float)h8[k];
        int u = lane * 8 + k;
        p0 += h * Wout[u * 3 + 0];
        p1 += h * Wout[u * 3 + 1];
        p2 += h * Wout[u * 3 + 2];
    }
    for (int off = 32; off; off >>= 1) {
        p0 += __shfl_down(p0, off, 64);
        p1 += __shfl_down(p1, off, 64);
        p2 += __shfl_down(p2, off, 64);
    }
    if (lane == 0) {
        int t = row >> 12, b = row & (B_ - 1);
        size_t o = ((size_t)b * T_ + t) * 3;
        out[o + 0] = p0 + bout[0];
        out[o + 1] = p1 + bout[1];
        out[o + 2] = p2 + bout[2];
    }
}

extern "C" void kernel_launch(void* const* d_in, const int* in_sizes, int n_in,
                              void* d_out, int out_size, void* d_ws, size_t ws_size,
                              hipStream_t stream) {
    const float* x   = (const float*)d_in[0];
    const float* W_r = (const float*)d_in[1];
    const float* b_r = (const float*)d_in[2];
    const float* W_q = (const float*)d_in[3];
    const float* b_q = (const float*)d_in[4];
    const float* W_s = (const float*)d_in[5];
    const float* b_s = (const float*)d_in[6];
    const float* W_o = (const float*)d_in[7];
    const float* b_o = (const float*)d_in[8];
    float* out = (float*)d_out;

    char* ws = (char*)d_ws;
    bf16_t* hhat  = (bf16_t*)ws; ws += (size_t)B_ * NRS * 2;           // 33.5 MB
    bf16_t* xtile = (bf16_t*)ws; ws += (size_t)T_ * XPT * 2;           // 33.5 MB
    bf16_t* hall  = (bf16_t*)ws; ws += (size_t)(T_ + 1) * B_ * U_ * 2; // 71 MB
    bf16_t* rh    = (bf16_t*)ws; ws += (size_t)B_ * U_ * 2;            // 4.2 MB
    bf16_t* WrsT  = (bf16_t*)ws; ws += (size_t)NC * K_ * 2;            // 12.6 MB
    bf16_t* Btile = (bf16_t*)ws; ws += (size_t)NC * K_ * 2;            // 12.6 MB
    bf16_t* htA   = (bf16_t*)ws; ws += (size_t)32 * HPH * 2;           // 4.2 MB
    bf16_t* htB   = (bf16_t*)ws; ws += (size_t)32 * HPH * 2;           // 4.2 MB
    bf16_t* Bq16  = (bf16_t*)ws; ws += (size_t)32 * QPP * 2;           // 0.79 MB
    float*  biasP = (float*)ws;  ws += (size_t)NC * 4;                 // 32 KB

    xtile_build<<<B_ * T_ * F_ / 8 / 256, 256, 0, stream>>>(x, xtile);
    transpose_perm<<<dim3(K_ / 32, NRS / 32), 256, 0, stream>>>(W_r, WrsT);
    transpose_perm<<<dim3(K_ / 32, NRS / 32), 256, 0, stream>>>(W_s, WrsT + (size_t)NRS * K_);
    btile_build<<<NC * 3, 256, 0, stream>>>(WrsT, Btile);
    bq16_build<<<K_ * U_ / 256, 256, 0, stream>>>(W_q, Bq16);
    bias_perm<<<NC / 256, 256, 0, stream>>>(b_r, b_s, biasP);

    // htile double buffer: read (t-1) from ht[t&1], write (t) to ht[(t+1)&1]
    bf16_t* htbuf[2] = {htA, htB};
    for (int t = 0; t < T_; t++) {
        const bf16_t* xt_t = xtile + (size_t)t * XPT;
        const bf16_t* htr  = htbuf[t & 1];
        bf16_t*       htw  = htbuf[(t + 1) & 1];
        bf16_t*       hn   = hall + (size_t)(t + 1) * B_ * U_;
        if (t == 0) {
            gemm_sq<1><<<dim3(32, 32), 256, 0, stream>>>(
                xt_t, htr, Btile, biasP, rh, Bq16, b_q, hhat, hn, htw);
        } else {
            gemm_r<<<dim3(32, 32), 256, 0, stream>>>(
                xt_t, htr, Btile, biasP, hhat, rh);
            gemm_sq<0><<<dim3(32, 32), 256, 0, stream>>>(
                xt_t, htr, Btile, biasP, rh, Bq16, b_q, hhat, hn, htw);
        }
    }
    out_all<<<B_ * T_ / 4, 256, 0, stream>>>(hall + (size_t)B_ * U_, W_o, b_o, out);
}